// Round 2
// baseline (602.663 us; speedup 1.0000x reference)
//
#include <hip/hip_runtime.h>
#include <math.h>

// Tiny 2-token transformer, E=30, H=3, D=10, B=1e6.
// Only token 1's logits are returned => post-attention path for token 1 only; q0 never needed.
// Round 2: fully-unrolled, all-register dataflow. No LDS. Weights are wave-uniform
// scalar loads (compile-time offsets -> s_load_dwordx8/16), activations in VGPRs.
// k0/k1 and v0/v1 are computed on-the-fly per output feature (each is used once),
// capping peak live registers at ~x0,x1 (60) + 30 accumulators + temps.

#define EPS 1e-5f

__device__ __forceinline__ float gelu_exact(float x) {
    return 0.5f * x * (1.0f + erff(x * 0.70710678118654752f));
}

__global__ __launch_bounds__(256, 3) void model_kernel(
    const float* __restrict__ input,   // [B,2,5]
    const float* __restrict__ w_emb,   // [30,5]
    const float* __restrict__ b_emb,   // [30]
    const float* __restrict__ w_in,    // [90,30]
    const float* __restrict__ b_in,    // [90]
    const float* __restrict__ w_out,   // [30,30]
    const float* __restrict__ b_out,   // [30]
    const float* __restrict__ w1,      // [30,30]
    const float* __restrict__ b1,      // [30]
    const float* __restrict__ w2,      // [30,30]
    const float* __restrict__ b2,      // [30]
    const float* __restrict__ gamma,   // [30]
    const float* __restrict__ beta,    // [30]
    const float* __restrict__ w_o,     // [3,30]
    const float* __restrict__ b_o,     // [3]
    float* __restrict__ out,           // [B,3]
    int B)
{
    const int e = blockIdx.x * 256 + threadIdx.x;
    if (e >= B) return;

    // ---- load input tokens (coalesced 40B/thread)
    float in0[5], in1[5];
    const float* ip = input + (long)e * 10;
    #pragma unroll
    for (int i = 0; i < 5; ++i) { in0[i] = ip[i]; in1[i] = ip[5 + i]; }

    // ---- embed + exact GELU -> x0, x1 (registers)
    float x0[30], x1[30];
    #pragma unroll
    for (int d = 0; d < 30; ++d) {
        float b = b_emb[d];
        float a0 = b, a1 = b;
        #pragma unroll
        for (int j = 0; j < 5; ++j) {
            float w = w_emb[d * 5 + j];
            a0 = fmaf(w, in0[j], a0);
            a1 = fmaf(w, in1[j], a1);
        }
        x0[d] = gelu_exact(a0);
        x1[d] = gelu_exact(a1);
    }

    // ---- q1 (token 1 query only)
    float q1[30];
    #pragma unroll
    for (int f = 0; f < 30; ++f) {
        float a = b_in[f], a2 = 0.0f;
        #pragma unroll
        for (int j = 0; j < 15; ++j) {
            a  = fmaf(w_in[f * 30 + j],      x1[j],      a);
            a2 = fmaf(w_in[f * 30 + 15 + j], x1[15 + j], a2);
        }
        q1[f] = a + a2;
    }

    // ---- scores + softmax per head; k0/k1 computed on the fly (used once each)
    float a0c[3], a1c[3];
    #pragma unroll
    for (int h = 0; h < 3; ++h) {
        float s10 = 0.0f, s11 = 0.0f;
        #pragma unroll
        for (int d = 0; d < 10; ++d) {
            const int f = h * 10 + d;
            float k0a = b_in[30 + f], k0b = 0.0f, k1a = k0a, k1b = 0.0f;
            #pragma unroll
            for (int j = 0; j < 15; ++j) {
                float wa = w_in[(30 + f) * 30 + j];
                float wb = w_in[(30 + f) * 30 + 15 + j];
                k0a = fmaf(wa, x0[j], k0a);
                k0b = fmaf(wb, x0[15 + j], k0b);
                k1a = fmaf(wa, x1[j], k1a);
                k1b = fmaf(wb, x1[15 + j], k1b);
            }
            float q = q1[f];
            s10 = fmaf(q, k0a + k0b, s10);
            s11 = fmaf(q, k1a + k1b, s11);
        }
        s10 *= 0.31622776601683794f;  // 1/sqrt(10)
        s11 *= 0.31622776601683794f;
        float m = fmaxf(s10, s11);
        float e0 = __expf(s10 - m), e1 = __expf(s11 - m);
        float inv = 1.0f / (e0 + e1);
        a0c[h] = e0 * inv;
        a1c[h] = e1 * inv;
    }

    // ---- ctx (token 1); v0/v1 computed on the fly (each feeds only ctx[f])
    float ctx[30];
    #pragma unroll
    for (int f = 0; f < 30; ++f) {
        float v0a = b_in[60 + f], v0b = 0.0f, v1a = v0a, v1b = 0.0f;
        #pragma unroll
        for (int j = 0; j < 15; ++j) {
            float wa = w_in[(60 + f) * 30 + j];
            float wb = w_in[(60 + f) * 30 + 15 + j];
            v0a = fmaf(wa, x0[j], v0a);
            v0b = fmaf(wb, x0[15 + j], v0b);
            v1a = fmaf(wa, x1[j], v1a);
            v1b = fmaf(wb, x1[15 + j], v1b);
        }
        const int h = f / 10;
        ctx[f] = a0c[h] * (v0a + v0b) + a1c[h] * (v1a + v1b);
    }
    // x0 dead from here.

    // ---- attn_out + residual(x1) + LayerNorm -> y
    float t[30];
    #pragma unroll
    for (int f = 0; f < 30; ++f) {
        float a = b_out[f], a2 = 0.0f;
        #pragma unroll
        for (int j = 0; j < 15; ++j) {
            a  = fmaf(w_out[f * 30 + j],      ctx[j],      a);
            a2 = fmaf(w_out[f * 30 + 15 + j], ctx[15 + j], a2);
        }
        t[f] = a + a2;
    }
    float mu = 0.0f;
    #pragma unroll
    for (int f = 0; f < 30; ++f) { t[f] += x1[f]; mu += t[f]; }
    mu *= (1.0f / 30.0f);
    float var = 0.0f;
    #pragma unroll
    for (int f = 0; f < 30; ++f) { float d = t[f] - mu; var = fmaf(d, d, var); }
    float rs = rsqrtf(var * (1.0f / 30.0f) + EPS);
    float y[30];
    #pragma unroll
    for (int f = 0; f < 30; ++f) y[f] = (t[f] - mu) * rs * gamma[f] + beta[f];
    // ctx, x1 dead.

    // ---- FFN layer 1 + exact GELU -> g
    float g[30];
    #pragma unroll
    for (int f = 0; f < 30; ++f) {
        float a = b1[f], a2 = 0.0f;
        #pragma unroll
        for (int j = 0; j < 15; ++j) {
            a  = fmaf(w1[f * 30 + j],      y[j],      a);
            a2 = fmaf(w1[f * 30 + 15 + j], y[15 + j], a2);
        }
        g[f] = gelu_exact(a + a2);
    }

    // ---- FFN layer 2 + residual(y) + LayerNorm -> t
    #pragma unroll
    for (int f = 0; f < 30; ++f) {
        float a = b2[f], a2 = 0.0f;
        #pragma unroll
        for (int j = 0; j < 15; ++j) {
            a  = fmaf(w2[f * 30 + j],      g[j],      a);
            a2 = fmaf(w2[f * 30 + 15 + j], g[15 + j], a2);
        }
        t[f] = a + a2;
    }
    mu = 0.0f;
    #pragma unroll
    for (int f = 0; f < 30; ++f) { t[f] += y[f]; mu += t[f]; }
    mu *= (1.0f / 30.0f);
    var = 0.0f;
    #pragma unroll
    for (int f = 0; f < 30; ++f) { float d = t[f] - mu; var = fmaf(d, d, var); }
    rs = rsqrtf(var * (1.0f / 30.0f) + EPS);
    #pragma unroll
    for (int f = 0; f < 30; ++f) t[f] = (t[f] - mu) * rs * gamma[f] + beta[f];

    // ---- logits for token 1
    #pragma unroll
    for (int o = 0; o < 3; ++o) {
        float a = b_o[o];
        #pragma unroll
        for (int j = 0; j < 30; ++j) a = fmaf(w_o[o * 30 + j], t[j], a);
        out[(long)e * 3 + o] = a;
    }
}

extern "C" void kernel_launch(void* const* d_in, const int* in_sizes, int n_in,
                              void* d_out, int out_size, void* d_ws, size_t ws_size,
                              hipStream_t stream) {
    const float* input = (const float*)d_in[0];
    const float* w_emb = (const float*)d_in[1];
    const float* b_emb = (const float*)d_in[2];
    const float* w_in  = (const float*)d_in[3];
    const float* b_in  = (const float*)d_in[4];
    const float* w_out = (const float*)d_in[5];
    const float* b_out = (const float*)d_in[6];
    const float* w1    = (const float*)d_in[7];
    const float* b1    = (const float*)d_in[8];
    const float* w2    = (const float*)d_in[9];
    const float* b2    = (const float*)d_in[10];
    const float* gamma = (const float*)d_in[11];
    const float* beta  = (const float*)d_in[12];
    const float* w_o   = (const float*)d_in[13];
    const float* b_o   = (const float*)d_in[14];
    float* out = (float*)d_out;

    const int B = in_sizes[0] / 10;
    const int blocks = (B + 255) / 256;
    model_kernel<<<blocks, 256, 0, stream>>>(
        input, w_emb, b_emb, w_in, b_in, w_out, b_out, w1, b1, w2, b2,
        gamma, beta, w_o, b_o, out, B);
}

// Round 4
// 107.048 us; speedup vs baseline: 5.6298x; 5.6298x over previous
//
#include <hip/hip_runtime.h>
#include <math.h>

// Tiny 2-token transformer, E=30, H=3, D=10, B=1e6 — transposed-MFMA version.
// Every layer computed as Y^T = W·X^T with mfma_f32_16x16x32_f16:
//   A operand = weights (prep-packed, bias folded at k=30),
//   B operand = activations^T (built from previous layer's C-regs by pure
//   register packing — the C/D layout row=4g+r matches B slot k=κ(g,e)).
// κ(g,e) = e<4 ? 4g+e : 16+4g+(e-4), used identically for A (prep) and B
// (repack) — mathematically inert for any actual hardware k-map as long as
// A and B share it. Lane (c,g): c = batch column, regs = feats 4g+r (tile0)
// and 16+4g+r (tile1). Pads (feat 30,31 / k=31) are exact zeros.
// LN/softmax: per-lane sums over 8 regs + shfl_xor(16,32) across g.

typedef _Float16 h8 __attribute__((ext_vector_type(8)));
typedef float f4 __attribute__((ext_vector_type(4)));
typedef f4 f4u __attribute__((aligned(4)));

#define EPS 1e-5f

__device__ __forceinline__ f4 MF(h8 a, h8 b, f4 c) {
    return __builtin_amdgcn_mfma_f32_16x16x32_f16(a, b, c, 0, 0, 0);
}

// Branch-free exact-GELU: erf via Abramowitz-Stegun 7.1.26 (|eps|<=1.5e-7).
// gelu(x) = 0.5x + 0.5|x|*(1 - poly(t)*exp(-z^2)), z = x/sqrt(2).
__device__ __forceinline__ float geluf(float x) {
    float z  = x * 0.70710678118654752f;
    float az = fabsf(z);
    float t  = __builtin_amdgcn_rcpf(fmaf(0.3275911f, az, 1.0f));
    float p  = fmaf(1.061405429f, t, -1.453152027f);
    p = fmaf(p, t, 1.421413741f);
    p = fmaf(p, t, -0.284496736f);
    p = fmaf(p, t, 0.254829592f);
    p = p * t;
    float ex = __expf(-z * z);
    float r  = fmaf(-p, ex, 1.0f);          // erf(|z|)
    return fmaf(0.5f * fabsf(x), r, 0.5f * x);
}

// Pack two C-tiles (f32) into a B-fragment (f16). g3 lanes: slot6 = 1.0 (bias
// row k=30), slot7 = 0 (k=31 pad).
__device__ __forceinline__ h8 pack_b(f4 t0, f4 t1, bool g3) {
    union { unsigned u[4]; h8 v; } r;
    r.u[0] = __builtin_bit_cast(unsigned, __builtin_amdgcn_cvt_pkrtz(t0[0], t0[1]));
    r.u[1] = __builtin_bit_cast(unsigned, __builtin_amdgcn_cvt_pkrtz(t0[2], t0[3]));
    r.u[2] = __builtin_bit_cast(unsigned, __builtin_amdgcn_cvt_pkrtz(t1[0], t1[1]));
    r.u[3] = g3 ? 0x3C00u
                : __builtin_bit_cast(unsigned, __builtin_amdgcn_cvt_pkrtz(t1[2], t1[3]));
    return r.v;
}

// ---- prep: pack weights as A-fragments with κ(g,e); bias folded at k=30.
// Tiles (512 halves each): 0,1 w_emb | 2,3 w_q(*S) | 4,5 w_k | 6,7 w_v
// | 8,9 w_out | 10,11 w1 | 12,13 w2 | 14 w_o. Then gamma[32],beta[32] floats.
__global__ void prep(const float* __restrict__ w_emb, const float* __restrict__ b_emb,
                     const float* __restrict__ w_in,  const float* __restrict__ b_in,
                     const float* __restrict__ w_out, const float* __restrict__ b_out,
                     const float* __restrict__ w1,    const float* __restrict__ b1,
                     const float* __restrict__ w2,    const float* __restrict__ b2,
                     const float* __restrict__ gamma, const float* __restrict__ beta,
                     const float* __restrict__ w_o,   const float* __restrict__ b_o,
                     unsigned short* __restrict__ ws) {
    int t = blockIdx.x * 256 + threadIdx.x;
    const float S = 0.31622776601683794f;   // 1/sqrt(10)
    if (t < 960) {
        int tile = t >> 6, lane = t & 63;
        int g = lane >> 4;
        int mat = (tile == 14) ? 7 : (tile >> 1);
        int row = (tile & 1) * 16 + (lane & 15);   // output feature
        #pragma unroll
        for (int e = 0; e < 8; ++e) {
            int k = (e < 4) ? (4 * g + e) : (16 + 4 * g + (e - 4));
            float v = 0.f;
            switch (mat) {
              case 0: if (row<30) { if (k<5)  v = w_emb[row*5+k];        else if (k==30) v = b_emb[row]; } break;
              case 1: if (row<30) { if (k<30) v = w_in[row*30+k]*S;      else if (k==30) v = b_in[row]*S; } break;
              case 2: if (row<30) { if (k<30) v = w_in[(30+row)*30+k];   else if (k==30) v = b_in[30+row]; } break;
              case 3: if (row<30) { if (k<30) v = w_in[(60+row)*30+k];   else if (k==30) v = b_in[60+row]; } break;
              case 4: if (row<30) { if (k<30) v = w_out[row*30+k];       else if (k==30) v = b_out[row]; } break;
              case 5: if (row<30) { if (k<30) v = w1[row*30+k];          else if (k==30) v = b1[row]; } break;
              case 6: if (row<30) { if (k<30) v = w2[row*30+k];          else if (k==30) v = b2[row]; } break;
              case 7: if (row<3)  { if (k<30) v = w_o[row*30+k];         else if (k==30) v = b_o[row]; } break;
            }
            _Float16 hv = (_Float16)v;
            ws[tile * 512 + lane * 8 + e] = __builtin_bit_cast(unsigned short, hv);
        }
    } else if (t < 1024) {
        int f = t - 960;   // 0..63
        float* tab = (float*)(ws + 15 * 512);
        if (f < 32) tab[f] = (f < 30) ? gamma[f] : 0.f;
        else        tab[f] = (f - 32 < 30) ? beta[f - 32] : 0.f;
    }
}

#define RED2(x) { x += __shfl_xor(x, 16); x += __shfl_xor(x, 32); }

#define ITERS 8   // 16 elements per wave-iter

__global__ __launch_bounds__(256) void model_kernel(
    const float* __restrict__ input,
    const unsigned short* __restrict__ ws,
    float* __restrict__ out, int B)
{
    const int lane = threadIdx.x & 63;
    const int wv   = threadIdx.x >> 6;
    const int c    = lane & 15;     // batch column
    const int g    = lane >> 4;
    const bool g3  = (g == 3);
    const f4 Z = {0.f, 0.f, 0.f, 0.f};

    // ---- weight A-fragments (wave-wide, loop-invariant)
    const h8* wsf = (const h8*)ws;
    h8 Aemb0 = wsf[0*64+lane],  Aemb1 = wsf[1*64+lane];
    h8 Aq0   = wsf[2*64+lane],  Aq1   = wsf[3*64+lane];
    h8 Ak0   = wsf[4*64+lane],  Ak1   = wsf[5*64+lane];
    h8 Av0   = wsf[6*64+lane],  Av1   = wsf[7*64+lane];
    h8 Ao0   = wsf[8*64+lane],  Ao1   = wsf[9*64+lane];
    h8 A10   = wsf[10*64+lane], A11   = wsf[11*64+lane];
    h8 A20   = wsf[12*64+lane], A21   = wsf[13*64+lane];
    h8 Awo   = wsf[14*64+lane];

    const float* tab = (const float*)(ws + 15 * 512);
    f4 gaV0 = *(const f4*)&tab[4*g];        // gamma[4g+r]
    f4 gaV1 = *(const f4*)&tab[16+4*g];     // gamma[16+4g+r]
    f4 beV0 = *(const f4*)&tab[32+4*g];
    f4 beV1 = *(const f4*)&tab[48+4*g];

    for (int it = 0; it < ITERS; ++it) {
        const int eb = ((blockIdx.x * 4 + wv) * ITERS + it) * 16;
        int e = eb + c; if (e > B - 1) e = B - 1;
        const float* ip = input + (long)e * 10;

        // ---- embed B-frags (In^T): k=0..4 from input, k=30 bias row = 1.0
        f4u va = *(const f4u*)ip;        float v4 = ip[4];
        f4u vb = *(const f4u*)(ip + 5);  float v9 = ip[9];
        union { unsigned u[4]; h8 v; } bi0, bi1;
        unsigned pk01a = __builtin_bit_cast(unsigned, __builtin_amdgcn_cvt_pkrtz(va[0], va[1]));
        unsigned pk23a = __builtin_bit_cast(unsigned, __builtin_amdgcn_cvt_pkrtz(va[2], va[3]));
        unsigned pk4a  = __builtin_bit_cast(unsigned, __builtin_amdgcn_cvt_pkrtz(v4, 0.f));
        unsigned pk01b = __builtin_bit_cast(unsigned, __builtin_amdgcn_cvt_pkrtz(vb[0], vb[1]));
        unsigned pk23b = __builtin_bit_cast(unsigned, __builtin_amdgcn_cvt_pkrtz(vb[2], vb[3]));
        unsigned pk4b  = __builtin_bit_cast(unsigned, __builtin_amdgcn_cvt_pkrtz(v9, 0.f));
        bi0.u[0] = (g == 0) ? pk01a : ((g == 1) ? pk4a : 0u);
        bi0.u[1] = (g == 0) ? pk23a : 0u;
        bi0.u[2] = 0u;
        bi0.u[3] = g3 ? 0x3C00u : 0u;
        bi1.u[0] = (g == 0) ? pk01b : ((g == 1) ? pk4b : 0u);
        bi1.u[1] = (g == 0) ? pk23b : 0u;
        bi1.u[2] = 0u;
        bi1.u[3] = g3 ? 0x3C00u : 0u;

        // ---- embed + gelu (X^T in C-layout: reg r = feat 4g+r / 16+4g+r)
        f4 x0t0 = MF(Aemb0, bi0.v, Z);
        f4 x0t1 = MF(Aemb1, bi0.v, Z);
        f4 x1t0 = MF(Aemb0, bi1.v, Z);
        f4 x1t1 = MF(Aemb1, bi1.v, Z);
        #pragma unroll
        for (int r = 0; r < 4; ++r) {
            x0t0[r] = geluf(x0t0[r]); x0t1[r] = geluf(x0t1[r]);
            x1t0[r] = geluf(x1t0[r]); x1t1[r] = geluf(x1t1[r]);
        }

        // ---- QKV (q for token 1 only, pre-scaled by 1/sqrt(10))
        h8 Bx0 = pack_b(x0t0, x0t1, g3);
        h8 Bx1 = pack_b(x1t0, x1t1, g3);
        f4 q0t  = MF(Aq0, Bx1, Z), q1t  = MF(Aq1, Bx1, Z);
        f4 k0t0 = MF(Ak0, Bx0, Z), k0t1 = MF(Ak1, Bx0, Z);
        f4 k1t0 = MF(Ak0, Bx1, Z), k1t1 = MF(Ak1, Bx1, Z);
        f4 v0t0 = MF(Av0, Bx0, Z), v0t1 = MF(Av1, Bx0, Z);
        f4 v1t0 = MF(Av0, Bx1, Z), v1t1 = MF(Av1, Bx1, Z);

        // ---- scores per head (feat f: tile0 f=4g+r -> h0/h1; tile1 f=16+4g+r -> h1/h2)
        float s0h0=0.f, s0h1=0.f, s0h2=0.f, s1h0=0.f, s1h1=0.f, s1h2=0.f;
        #pragma unroll
        for (int r = 0; r < 4; ++r) {
            float p00 = q0t[r] * k0t0[r], p10 = q0t[r] * k1t0[r];
            bool c0 = (4 * g + r) < 10;
            s0h0 += c0 ? p00 : 0.f;  s0h1 += c0 ? 0.f : p00;
            s1h0 += c0 ? p10 : 0.f;  s1h1 += c0 ? 0.f : p10;
            float p01 = q1t[r] * k0t1[r], p11 = q1t[r] * k1t1[r];
            bool c1 = (16 + 4 * g + r) < 20;   // pads (30,31) -> h2, product 0
            s0h1 += c1 ? p01 : 0.f;  s0h2 += c1 ? 0.f : p01;
            s1h1 += c1 ? p11 : 0.f;  s1h2 += c1 ? 0.f : p11;
        }
        RED2(s0h0); RED2(s0h1); RED2(s0h2);
        RED2(s1h0); RED2(s1h1); RED2(s1h2);

        float m0 = fmaxf(s0h0, s1h0), m1 = fmaxf(s0h1, s1h1), m2 = fmaxf(s0h2, s1h2);
        float e00 = __expf(s0h0 - m0), e10 = __expf(s1h0 - m0);
        float e01 = __expf(s0h1 - m1), e11 = __expf(s1h1 - m1);
        float e02 = __expf(s0h2 - m2), e12 = __expf(s1h2 - m2);
        float i0 = 1.f / (e00 + e10), i1 = 1.f / (e01 + e11), i2 = 1.f / (e02 + e12);
        float a0h0 = e00*i0, a1h0 = e10*i0;
        float a0h1 = e01*i1, a1h1 = e11*i1;
        float a0h2 = e02*i2, a1h2 = e12*i2;

        // ---- ctx
        f4 ctx0, ctx1;
        #pragma unroll
        for (int r = 0; r < 4; ++r) {
            bool c0 = (4 * g + r) < 10;
            float A0 = c0 ? a0h0 : a0h1, A1 = c0 ? a1h0 : a1h1;
            ctx0[r] = A0 * v0t0[r] + A1 * v1t0[r];
            bool c1 = (16 + 4 * g + r) < 20;
            float B0 = c1 ? a0h1 : a0h2, B1 = c1 ? a1h1 : a1h2;
            ctx1[r] = B0 * v0t1[r] + B1 * v1t1[r];
        }

        // ---- attn out + residual(x1) via C-in
        h8 Bc = pack_b(ctx0, ctx1, g3);
        f4 t0 = MF(Ao0, Bc, x1t0);
        f4 t1 = MF(Ao1, Bc, x1t1);

        // ---- LN1 (per-lane batch: mu, rs are lane scalars)
        float s = 0.f, ss = 0.f;
        #pragma unroll
        for (int r = 0; r < 4; ++r) {
            s += t0[r] + t1[r];
            ss += t0[r]*t0[r] + t1[r]*t1[r];
        }
        RED2(s); RED2(ss);
        float mu = s * (1.f/30.f);
        float rs = rsqrtf(ss * (1.f/30.f) - mu*mu + EPS);
        f4 y0, y1;
        #pragma unroll
        for (int r = 0; r < 4; ++r) {
            y0[r] = fmaf((t0[r]-mu)*rs, gaV0[r], beV0[r]);
            y1[r] = fmaf((t1[r]-mu)*rs, gaV1[r], beV1[r]);
        }

        // ---- FFN1 + gelu
        h8 By = pack_b(y0, y1, g3);
        f4 hh0 = MF(A10, By, Z), hh1 = MF(A11, By, Z);
        #pragma unroll
        for (int r = 0; r < 4; ++r) { hh0[r] = geluf(hh0[r]); hh1[r] = geluf(hh1[r]); }

        // ---- FFN2 + residual(y) via C-in
        h8 Bh = pack_b(hh0, hh1, g3);
        f4 u0 = MF(A20, Bh, y0), u1 = MF(A21, Bh, y1);

        // ---- LN2
        s = 0.f; ss = 0.f;
        #pragma unroll
        for (int r = 0; r < 4; ++r) {
            s += u0[r] + u1[r];
            ss += u0[r]*u0[r] + u1[r]*u1[r];
        }
        RED2(s); RED2(ss);
        mu = s * (1.f/30.f);
        rs = rsqrtf(ss * (1.f/30.f) - mu*mu + EPS);
        f4 w0, w1;
        #pragma unroll
        for (int r = 0; r < 4; ++r) {
            w0[r] = fmaf((u0[r]-mu)*rs, gaV0[r], beV0[r]);
            w1[r] = fmaf((u1[r]-mu)*rs, gaV1[r], beV1[r]);
        }

        // ---- logits (rows 0..2 of tile0 => g==0, regs 0..2)
        h8 Bw = pack_b(w0, w1, g3);
        f4 lg = MF(Awo, Bw, Z);
        if (g == 0 && eb + c < B) {
            long base = (long)(eb + c) * 3;
            out[base]     = lg[0];
            out[base + 1] = lg[1];
            out[base + 2] = lg[2];
        }
    }
}

extern "C" void kernel_launch(void* const* d_in, const int* in_sizes, int n_in,
                              void* d_out, int out_size, void* d_ws, size_t ws_size,
                              hipStream_t stream) {
    const float* input = (const float*)d_in[0];
    const float* w_emb = (const float*)d_in[1];
    const float* b_emb = (const float*)d_in[2];
    const float* w_in  = (const float*)d_in[3];
    const float* b_in  = (const float*)d_in[4];
    const float* w_out = (const float*)d_in[5];
    const float* b_out = (const float*)d_in[6];
    const float* w1    = (const float*)d_in[7];
    const float* b1    = (const float*)d_in[8];
    const float* w2    = (const float*)d_in[9];
    const float* b2    = (const float*)d_in[10];
    const float* gamma = (const float*)d_in[11];
    const float* beta  = (const float*)d_in[12];
    const float* w_o   = (const float*)d_in[13];
    const float* b_o   = (const float*)d_in[14];
    float* out = (float*)d_out;
    unsigned short* ws = (unsigned short*)d_ws;   // 15*1KB tiles + 256B tables

    const int B = in_sizes[0] / 10;

    prep<<<4, 256, 0, stream>>>(w_emb, b_emb, w_in, b_in, w_out, b_out,
                                w1, b1, w2, b2, gamma, beta, w_o, b_o, ws);

    const int per_block = 4 * ITERS * 16;   // 512 elements
    const int blocks = (B + per_block - 1) / per_block;
    model_kernel<<<blocks, 256, 0, stream>>>(input, ws, out, B);
}